// Round 7
// baseline (11156.625 us; speedup 1.0000x reference)
//
#include <hip/hip_runtime.h>

// B=128, S=1024, F_IN=128, H=256, BB=256, F_OUT=128
#define Bn   128
#define Sn   1024
#define FIN  128
#define Hn   256
#define FOUT 128
#define KBB  384
#define NT1  512

// ---- fallback cfc5 (round-5 best measured: 3980 us) ----
#define NR4 20
#define NL4 1
#define DYN_SMEM ((32 * 256 * 8 + NL4 * 1024 * 8) * 2)

// ---- pair-split cfc6: 2 WGs per row, 256 WGs = 256 CUs ----
// LDS per WG: Wb_h half (16 chunks x 256 cols) 64 KB + NL6 W4 chunks
// (512 cols each) 88 KB = 152 KB dyn; streamed 21 chunks = 168 KB/step
// (10 prefetched to regs at loop top to overlap Z+sync with the L2 port).
#define NL6 11
#define PF6 10
#define DYN6 ((16 * 256 * 8 + NL6 * 512 * 8) * 2)   // 155648 B

// packed weight layout in d_ws (halves):
//   Wb_p [48][256][8]  (chunks 0-15 = x-part, 16-47 = h-part)
//   W4_p [32][1024][8] (N = [ff1|ff2|ta|tb])
//   Wo_p [32][128][8]
//   hbuf [B*S*H] fp16 ; xc [B*S*BB] fp16 ; mbox fp32 ; cnt u32
#define WB_OFF 0
#define W4_OFF 98304
#define WO_OFF 360448
#define WS_HALVES 393216
#define HBUF_OFF WS_HALVES
#define XC_OFF (HBUF_OFF + (size_t)Bn * Sn * Hn)
#define WS_SPLIT_BYTES ((size_t)(WS_HALVES + (size_t)Bn * Sn * Hn) * 2)
#define WS_FULL_BYTES ((XC_OFF + (size_t)Bn * Sn * Hn) * 2)
#define MBOX_BYTE_OFF WS_FULL_BYTES
#define MBOX_FLOATS ((size_t)Bn * 2 * 2 * 256)          // [row][hf][buf][256]
#define CNT_BYTE_OFF (MBOX_BYTE_OFF + MBOX_FLOATS * 4)
#define WS_PAIR_BYTES (CNT_BYTE_OFF + 256 * 4)

typedef _Float16 h2 __attribute__((ext_vector_type(2)));
typedef _Float16 h8 __attribute__((ext_vector_type(8)));

__device__ __forceinline__ float dot2f(h2 a, h2 b, float c) {
#if __has_builtin(__builtin_amdgcn_fdot2)
  return __builtin_amdgcn_fdot2(a, b, c, false);   // v_dot2_f32_f16
#else
  return c + (float)a[0] * (float)b[0] + (float)a[1] * (float)b[1];
#endif
}
__device__ __forceinline__ void dot8_4(h8 v, h8 w, float& c0, float& c1, float& c2, float& c3) {
  h2 v0 = {v[0], v[1]}, v1 = {v[2], v[3]}, v2 = {v[4], v[5]}, v3 = {v[6], v[7]};
  h2 w0 = {w[0], w[1]}, w1 = {w[2], w[3]}, w2 = {w[4], w[5]}, w3 = {w[6], w[7]};
  c0 = dot2f(v0, w0, c0); c1 = dot2f(v1, w1, c1);
  c2 = dot2f(v2, w2, c2); c3 = dot2f(v3, w3, c3);
}

// fp32 -> fp16 packing (verified layout)
__global__ __launch_bounds__(256) void pack_w(
    const float* __restrict__ Wb, const float* __restrict__ W1,
    const float* __restrict__ W2, const float* __restrict__ W3,
    const float* __restrict__ W4, const float* __restrict__ Wo,
    _Float16* __restrict__ ws) {
  int p = blockIdx.x * 256 + threadIdx.x;
  if (p >= WS_HALVES) return;
  float v;
  if (p < W4_OFF) {                       // backbone [384,256] row-major
    int r = p & 7, j = (p >> 3) & 255;
    int k = ((p >> 11) << 3) | r;
    v = Wb[k * 256 + j];
  } else if (p < WO_OFF) {                // heads concat: N = [ff1|ff2|ta|tb]
    int q = p - W4_OFF;
    int r = q & 7, j = (q >> 3) & 1023;
    int k = ((q >> 13) << 3) | r;
    int jj = j & 255;
    const float* Ws = (j < 256) ? W1 : (j < 512) ? W2 : (j < 768) ? W3 : W4;
    v = Ws[k * 256 + jj];
  } else {                                // Wout [256,128]
    int q = p - WO_OFF;
    int r = q & 7, j = (q >> 3) & 127;
    int k = ((q >> 10) << 3) | r;
    v = Wo[k * 128 + j];
  }
  ws[p] = (_Float16)v;
}

__global__ void zcnt(unsigned* __restrict__ c) { c[threadIdx.x] = 0; }

// xc[r,j] = sum_k x[r,k] * Wb[k,j]  (k<128, non-recurrent x-part of Z)
__global__ __launch_bounds__(256) void xgemm(
    const float* __restrict__ x, const _Float16* __restrict__ ws,
    _Float16* __restrict__ xc) {
  __shared__ __align__(16) _Float16 sX[64 * 128];   // 16 KB
  const int tid = threadIdx.x;
  const size_t r0 = (size_t)blockIdx.x * 64;
  const float* xb = x + r0 * 128;
#pragma unroll
  for (int m = 0; m < 32; ++m)
    sX[m * 256 + tid] = (_Float16)xb[m * 256 + tid];
  const _Float16* gX = ws + WB_OFF + (size_t)tid * 8;   // chunks 0-15 = x-part
  h8 wx[16];
#pragma unroll
  for (int L = 0; L < 16; ++L) wx[L] = *(const h8*)(gX + (size_t)L * 2048);
  __syncthreads();
  for (int r = 0; r < 64; ++r) {
    float c0 = 0.f, c1 = 0.f, c2 = 0.f, c3 = 0.f;
#pragma unroll
    for (int L = 0; L < 16; ++L) {
      h8 v = *(const h8*)&sX[r * 128 + L * 8];          // broadcast
      dot8_4(v, wx[L], c0, c1, c2, c3);
    }
    xc[(r0 + r) * 256 + tid] = (_Float16)(c0 + c1 + c2 + c3);
  }
}

// Pair-split recurrent kernel. WG (row = blockIdx&127, hf = blockIdx>>7).
// Pairs (i, i+128) share an XCD under round-robin dispatch (perf heuristic
// only; agent-scope atomics keep it correct regardless of placement).
// Per step:  Z-partial over OWN h-half (Wb_h half LDS-resident)
//           -> exchange z-partials with partner (1 KB, ping-pong mailbox)
//           -> full zf local -> heads for own 128 h-cols (4x128 W4 cols:
//              11 chunks LDS, 10 reg-prefetched at loop top, 11 streamed)
//           -> own h-half locally (it IS the Z K-half: no h exchange).
__global__ __launch_bounds__(NT1) void cfc6(
    const float* __restrict__ ts, const float* __restrict__ bb,
    const float* __restrict__ bf1, const float* __restrict__ bf2,
    const float* __restrict__ bta, const float* __restrict__ btb,
    _Float16* __restrict__ ws, unsigned* __restrict__ cnt,
    float* __restrict__ mbox) {
  __shared__ __align__(16) _Float16 hl[128];     // own h half
  __shared__ __align__(16) _Float16 zfs[Hn];     // full z (fp16)
  __shared__ float tsb[Sn];
  __shared__ float scrZ[256];
  __shared__ float scrH[384];
  extern __shared__ __align__(16) _Float16 dyn[];
  _Float16* sWbh = dyn;                  // [16][256][8] = 64 KB
  _Float16* sW4L = dyn + 16 * 256 * 8;   // [NL6][512][8] = 88 KB

  const int tid = threadIdx.x;
  const int row = blockIdx.x & 127;
  const int hf  = blockIdx.x >> 7;

  const _Float16* Wb_p = ws + WB_OFF;
  const _Float16* W4_p = ws + W4_OFF;
  _Float16* hbuf = ws + HBUF_OFF;
  const _Float16* xcp = ws + XC_OFF;
  const float* tsrow = ts + (size_t)row * Sn;

  const int jz = tid & 255, kq = tid >> 8;       // Z roles
  const int head = tid >> 7, jj = tid & 127;     // H roles
  const int jcol = head * 256 + hf * 128 + jj;   // packed W4 col
  const float bbj = (tid < 256) ? bb[tid] : 0.f;
  const float bH =
      (head == 0 ? bf1 : head == 1 ? bf2 : head == 2 ? bta : btb)[hf * 128 + jj];
  const _Float16* gH = W4_p + (size_t)jcol * 8;

  // ---- one-time staging ----
  {  // Wb_h rows for own h-half: chunks 16+hf*16 .. +16
    const h8* src = (const h8*)(Wb_p + (size_t)(16 + hf * 16) * 2048);
    h8* dst = (h8*)sWbh;
    for (int i = tid; i < 16 * 256; i += NT1) dst[i] = src[i];
  }
#pragma unroll
  for (int c = 0; c < NL6; ++c)                  // W4 chunks 0..NL6 (own cols)
    *(h8*)&sW4L[((size_t)c * 512 + tid) * 8] = *(const h8*)(gH + (size_t)c * 8192);
  for (int i = tid; i < Sn; i += NT1) tsb[i] = tsrow[i];
  if (tid < 128) hl[tid] = (_Float16)0.f;        // h0 = 0

  float* mb_me       = mbox + (size_t)(row * 2 + hf) * 512;        // [2][256]
  const float* mb_pt = mbox + (size_t)(row * 2 + (1 - hf)) * 512;
  unsigned* c_me = cnt + row * 2 + hf;
  unsigned* c_pt = cnt + row * 2 + (1 - hf);
  __syncthreads();

  for (unsigned st = 0; st < Sn; ++st) {
    // reg-prefetch of streamed W4 chunks: L2 port works during Z + sync
    h8 wpf[PF6];
#pragma unroll
    for (int c = 0; c < PF6; ++c)
      wpf[c] = *(const h8*)(gH + (size_t)(NL6 + c) * 8192);
    float xcv = 0.f;
    if (tid < 256) xcv = (float)xcp[((size_t)row * Sn + st) * 256 + tid];

    // ---- Z partial: own K-half (h-local), all 256 cols ----
    float a0 = 0.f, a1 = 0.f, a2 = 0.f, a3 = 0.f;
#pragma unroll
    for (int c = kq * 8; c < kq * 8 + 8; ++c) {
      h8 v = *(const h8*)&hl[c * 8];                       // broadcast
      h8 w = *(const h8*)&sWbh[((size_t)c * 256 + jz) * 8];
      dot8_4(v, w, a0, a1, a2, a3);
    }
    float zs = a0 + a1 + a2 + a3;
    if (kq) scrZ[jz] = zs;
    __syncthreads();                       // B1
    float zp = 0.f;
    if (tid < 256) {
      zp = zs + scrZ[tid];
      __hip_atomic_store(&mb_me[(st & 1) * 256 + tid], zp,
                         __ATOMIC_RELAXED, __HIP_MEMORY_SCOPE_AGENT);
    }
    __syncthreads();                       // B2: stores drained (vmcnt0@barrier)
    if (tid == 0) {
      __hip_atomic_fetch_add(c_me, 1u, __ATOMIC_RELEASE, __HIP_MEMORY_SCOPE_AGENT);
      while (__hip_atomic_load(c_pt, __ATOMIC_ACQUIRE, __HIP_MEMORY_SCOPE_AGENT) <= st)
        __builtin_amdgcn_s_sleep(1);
    }
    __syncthreads();                       // B3: partner data published
    if (tid < 256) {
      float pz = __hip_atomic_load(&mb_pt[(st & 1) * 256 + tid],
                                   __ATOMIC_RELAXED, __HIP_MEMORY_SCOPE_AGENT);
      zfs[tid] = (_Float16)tanhf(zp + pz + xcv + bbj);
    }
    __syncthreads();                       // B4: zf ready

    // ---- H: own col of [ff1|ff2|ta|tb], K=256 ----
    float s0 = 0.f, s1 = 0.f, s2 = 0.f, s3 = 0.f;
#pragma unroll 2
    for (int c = NL6 + PF6; c < 32; ++c) {               // streamed tail
      h8 v = *(const h8*)&zfs[c * 8];
      h8 w = *(const h8*)(gH + (size_t)c * 8192);
      dot8_4(v, w, s0, s1, s2, s3);
    }
#pragma unroll
    for (int c = 0; c < PF6; ++c) {                       // prefetched
      h8 v = *(const h8*)&zfs[(NL6 + c) * 8];
      dot8_4(v, wpf[c], s0, s1, s2, s3);
    }
    float b0 = 0.f, b1 = 0.f, b2 = 0.f, b3 = 0.f;
#pragma unroll
    for (int c = 0; c < NL6; ++c) {                       // LDS-resident
      h8 v = *(const h8*)&zfs[c * 8];
      h8 w = *(const h8*)&sW4L[((size_t)c * 512 + tid) * 8];
      dot8_4(v, w, b0, b1, b2, b3);
    }
    float g = (s0 + b0) + (s1 + b1) + (s2 + b2) + (s3 + b3) + bH;
    if (head) scrH[(head - 1) * 128 + jj] = g;
    __syncthreads();                       // B5
    if (head == 0) {
      float ff2 = scrH[jj], ta = scrH[128 + jj], tb = scrH[256 + jj];
      float tt = tsb[st];
      float sg = 1.f / (1.f + __expf(-(ta * tt + tb)));
      float hn = tanhf(g) * (1.f - sg) + sg * tanhf(ff2);
      hl[jj] = (_Float16)hn;
      hbuf[((size_t)row * Sn + st) * Hn + hf * 128 + jj] = (_Float16)hn;
    }
    __syncthreads();                       // B6: hl ready for next Z
  }
}

// ---- fallback: round-5 cfc5 (one WG per row) ----
template <int XC, int INLINE_Y>
__global__ __launch_bounds__(NT1, 2) void cfc5(
    const float* __restrict__ x, const float* __restrict__ ts,
    const float* __restrict__ bb, const float* __restrict__ bf1,
    const float* __restrict__ bf2, const float* __restrict__ bta,
    const float* __restrict__ btb, const float* __restrict__ bo,
    _Float16* __restrict__ ws, float* __restrict__ out) {
  __shared__ __align__(16) _Float16 xh[KBB];
  __shared__ __align__(16) _Float16 zf[Hn];
  __shared__ float tsb[Sn];
  __shared__ float scrZ[256];
  __shared__ float scrH[512];
  extern __shared__ __align__(16) _Float16 dyn[];
  _Float16* sWb  = dyn;                        // [32][256][8] = 128 KB (XC=1)
  _Float16* sW4L = dyn + 32 * 256 * 8;         // [NL4][1024][8] = 16 KB

  const int tid = threadIdx.x;
  const int b = blockIdx.x;
  const _Float16* Wb_p = ws + WB_OFF;
  const _Float16* W4_p = ws + W4_OFF;
  const _Float16* Wo_p = ws + WO_OFF;
  _Float16* hbuf = ws + HBUF_OFF;
  const _Float16* xcp = ws + XC_OFF;

  const float* xrow  = x  + (size_t)b * Sn * FIN;
  const float* tsrow = ts + (size_t)b * Sn;
  float*       orow  = out + (size_t)b * Sn * FOUT;

  const int jz = tid & 255, kz = tid >> 8;
  const float bbj = (tid < 256) ? bb[tid] : 0.f;
  const float bHA = (tid < 256) ? bf1[tid] : bf2[tid - 256];
  const float bHB = (tid < 256) ? bta[tid] : btb[tid - 256];
  const int jY = tid & 127, kqY = tid >> 7;
  const float boj = bo[jY];

  if (XC) {
    const h8* src = (const h8*)(Wb_p + (size_t)16 * 2048);
    h8* dst = (h8*)sWb;
    for (int i = tid; i < 8192; i += NT1) dst[i] = src[i];
  }
  {
    const h8* src = (const h8*)(W4_p + (size_t)NR4 * 8192);
    h8* dst = (h8*)sW4L;
    for (int i = tid; i < NL4 * 1024; i += NT1) dst[i] = src[i];
  }
  for (int i = tid; i < Sn; i += NT1) tsb[i] = tsrow[i];
  if (tid < 128) ((unsigned*)xh)[64 + tid] = 0;
  if (!XC && tid < 64) {
    float2 xv = *(const float2*)(xrow + 2 * tid);
    h2 p; p[0] = (_Float16)xv.x; p[1] = (_Float16)xv.y;
    *(h2*)&xh[2 * tid] = p;
  }

  const _Float16* gA = W4_p + (size_t)tid * 8;
  const _Float16* gB = W4_p + (size_t)(tid + 512) * 8;
  h8 wA[NR4], wBv[NR4];
#pragma unroll
  for (int c = 0; c < NR4; ++c) {
    wA[c]  = *(const h8*)(gA + (size_t)c * 8192);
    wBv[c] = *(const h8*)(gB + (size_t)c * 8192);
  }
#pragma unroll
  for (int c = 0; c < NR4; ++c) {
    asm volatile("" : "+v"(wA[c]));
    asm volatile("" : "+v"(wBv[c]));
  }
  __syncthreads();

  for (int st = 0; st < Sn; ++st) {
    float xcv = 0.f;
    if (XC && tid < 256)
      xcv = (float)xcp[((size_t)b * Sn + st) * 256 + tid];
    float2 xv; xv.x = 0.f; xv.y = 0.f;
    if (!XC && tid >= 448 && st + 1 < Sn)
      xv = *(const float2*)(xrow + (size_t)(st + 1) * FIN + 2 * (tid - 448));

    float a0 = 0.f, a1 = 0.f, a2 = 0.f, a3 = 0.f;
    if (XC) {
#pragma unroll 4
      for (int c = 0; c < 16; ++c) {
        int kc = kz * 16 + c;
        h8 v = *(const h8*)&xh[128 + kc * 8];
        h8 w = *(const h8*)&sWb[((size_t)kc * 256 + jz) * 8];
        dot8_4(v, w, a0, a1, a2, a3);
      }
    } else {
      const _Float16* gZ = Wb_p + ((size_t)(kz * 24) * 256 + jz) * 8;
#pragma unroll 4
      for (int c = 0; c < 24; ++c) {
        h8 v = *(const h8*)&xh[(kz * 24 + c) * 8];
        h8 w = *(const h8*)(gZ + (size_t)c * 2048);
        dot8_4(v, w, a0, a1, a2, a3);
      }
    }
    float zs = a0 + a1 + a2 + a3;
    if (kz) scrZ[jz] = zs;
    __syncthreads();
    if (tid < 256) {
      float zp = zs + scrZ[tid] + bbj;
      if (XC) zp += xcv;
      zf[tid] = (_Float16)tanhf(zp);
    }
    if (!XC && tid >= 448 && st + 1 < Sn) {
      h2 p; p[0] = (_Float16)xv.x; p[1] = (_Float16)xv.y;
      *(h2*)&xh[2 * (tid - 448)] = p;
    }
    __syncthreads();

    float hA0 = 0.f, hA1 = 0.f, hA2 = 0.f, hA3 = 0.f;
    float hB0 = 0.f, hB1 = 0.f, hB2 = 0.f, hB3 = 0.f;
#pragma unroll 2
    for (int c = NR4 + NL4; c < 32; ++c) {
      h8 v  = *(const h8*)&zf[c * 8];
      h8 wa = *(const h8*)(gA + (size_t)c * 8192);
      h8 wb = *(const h8*)(gB + (size_t)c * 8192);
      dot8_4(v, wa, hA0, hA1, hA2, hA3);
      dot8_4(v, wb, hB0, hB1, hB2, hB3);
    }
#pragma unroll
    for (int c = 0; c < NR4; ++c) {
      h8 v = *(const h8*)&zf[c * 8];
      dot8_4(v, wA[c],  hA0, hA1, hA2, hA3);
      dot8_4(v, wBv[c], hB0, hB1, hB2, hB3);
    }
#pragma unroll
    for (int l = 0; l < NL4; ++l) {
      h8 v  = *(const h8*)&zf[(NR4 + l) * 8];
      h8 wa = *(const h8*)&sW4L[((size_t)l * 1024 + tid) * 8];
      h8 wb = *(const h8*)&sW4L[((size_t)l * 1024 + tid + 512) * 8];
      dot8_4(v, wa, hA0, hA1, hA2, hA3);
      dot8_4(v, wb, hB0, hB1, hB2, hB3);
    }
    float gAv = hA0 + hA1 + hA2 + hA3 + bHA;
    float gBv = hB0 + hB1 + hB2 + hB3 + bHB;
    if (tid >= 256) {
      scrH[tid - 256]       = gAv;
      scrH[256 + tid - 256] = gBv;
    }
    __syncthreads();
    if (tid < 256) {
      float ff2v = scrH[tid], tbv = scrH[256 + tid];
      float tt = tsb[st];
      float sg = 1.f / (1.f + __expf(-(gBv * tt + tbv)));
      float hn = tanhf(gAv) * (1.f - sg) + sg * tanhf(ff2v);
      xh[128 + tid] = (_Float16)hn;
      if (!INLINE_Y)
        hbuf[((size_t)b * Sn + st) * Hn + tid] = (_Float16)hn;
    }
    __syncthreads();

    if (INLINE_Y) {
      const _Float16* gY = Wo_p + ((size_t)(kqY * 8) * 128 + jY) * 8;
      float y0 = 0.f, y1 = 0.f, y2 = 0.f, y3 = 0.f;
#pragma unroll
      for (int c = 0; c < 8; ++c) {
        h8 v = *(const h8*)&xh[128 + (kqY * 8 + c) * 8];
        h8 w = *(const h8*)(gY + (size_t)c * 1024);
        dot8_4(v, w, y0, y1, y2, y3);
      }
      float ysv = y0 + y1 + y2 + y3;
      if (kqY) scrH[(kqY - 1) * 128 + jY] = ysv;
      __syncthreads();
      if (kqY == 0) {
        float y = ysv + boj + scrH[jY] + scrH[128 + jY] + scrH[256 + jY];
        orow[(size_t)st * FOUT + jY] = y;
      }
    }
  }
}

// Phase 2 (split path): y[BS,128] = h[BS,256] @ Wout + bo
#define SMEMY (65536 + 4096)
extern "C" __global__ __launch_bounds__(256, 4)
void ygemm(const _Float16* __restrict__ ws, const float* __restrict__ bo,
           float* __restrict__ out) {
  extern __shared__ char ysm[];
  _Float16* sWo = (_Float16*)ysm;            // 32768 halves
  _Float16* sH  = (_Float16*)(ysm + 65536);  // 8 x 256 halves
  const int tid = threadIdx.x;
  { const uint4* g = (const uint4*)(ws + WO_OFF);
    uint4* l = (uint4*)sWo;
#pragma unroll
    for (int i = 0; i < 16; ++i) l[tid + 256 * i] = g[tid + 256 * i]; }
  const _Float16* hb = ws + HBUF_OFF;
  const int row0 = blockIdx.x * 256;
  const int j = tid & 127, rh = tid >> 7;
  const float boj = bo[j];
  for (int it = 0; it < 32; ++it) {
    const int rbase = row0 + it * 8;
    __syncthreads();
    ((uint4*)sH)[tid] = ((const uint4*)(hb + (size_t)rbase * 256))[tid];
    __syncthreads();
#pragma unroll
    for (int rr = rh; rr < 8; rr += 2) {
      float y0 = 0.f, y1 = 0.f, y2 = 0.f, y3 = 0.f;
#pragma unroll 4
      for (int c = 0; c < 32; ++c) {
        h8 v = *(const h8*)&sH[rr * 256 + c * 8];
        h8 w = *(const h8*)&sWo[((size_t)c * 128 + j) * 8];
        dot8_4(v, w, y0, y1, y2, y3);
      }
      out[(size_t)(rbase + rr) * 128 + j] = y0 + y1 + y2 + y3 + boj;
    }
  }
}

extern "C" void kernel_launch(void* const* d_in, const int* in_sizes, int n_in,
                              void* d_out, int out_size, void* d_ws, size_t ws_size,
                              hipStream_t stream) {
  const float* x   = (const float*)d_in[0];
  const float* ts  = (const float*)d_in[1];
  const float* Wb  = (const float*)d_in[2];
  const float* bb  = (const float*)d_in[3];
  const float* W1  = (const float*)d_in[4];
  const float* bf1 = (const float*)d_in[5];
  const float* W2  = (const float*)d_in[6];
  const float* bf2 = (const float*)d_in[7];
  const float* W3  = (const float*)d_in[8];
  const float* bta = (const float*)d_in[9];
  const float* W4  = (const float*)d_in[10];
  const float* btb = (const float*)d_in[11];
  const float* Wo  = (const float*)d_in[12];
  const float* bo  = (const float*)d_in[13];
  float* out = (float*)d_out;
  _Float16* ws = (_Float16*)d_ws;

  pack_w<<<WS_HALVES / 256, 256, 0, stream>>>(Wb, W1, W2, W3, W4, Wo, ws);

  if (ws_size >= WS_PAIR_BYTES) {
    zcnt<<<1, 256, 0, stream>>>((unsigned*)((char*)d_ws + CNT_BYTE_OFF));
    xgemm<<<(Bn * Sn) / 64, 256, 0, stream>>>(x, ws, ws + XC_OFF);
    hipFuncSetAttribute((const void*)cfc6,
                        hipFuncAttributeMaxDynamicSharedMemorySize, DYN6);
    cfc6<<<2 * Bn, NT1, DYN6, stream>>>(
        ts, bb, bf1, bf2, bta, btb, ws,
        (unsigned*)((char*)d_ws + CNT_BYTE_OFF),
        (float*)((char*)d_ws + MBOX_BYTE_OFF));
    hipFuncSetAttribute((const void*)ygemm,
                        hipFuncAttributeMaxDynamicSharedMemorySize, SMEMY);
    ygemm<<<(Bn * Sn) / 256, 256, SMEMY, stream>>>(ws, bo, out);
  } else if (ws_size >= WS_FULL_BYTES) {
    xgemm<<<(Bn * Sn) / 64, 256, 0, stream>>>(x, ws, ws + XC_OFF);
    hipFuncSetAttribute((const void*)(cfc5<1, 0>),
                        hipFuncAttributeMaxDynamicSharedMemorySize, DYN_SMEM);
    cfc5<1, 0><<<Bn, NT1, DYN_SMEM, stream>>>(x, ts, bb, bf1, bf2, bta, btb, bo, ws, out);
    hipFuncSetAttribute((const void*)ygemm,
                        hipFuncAttributeMaxDynamicSharedMemorySize, SMEMY);
    ygemm<<<(Bn * Sn) / 256, 256, SMEMY, stream>>>(ws, bo, out);
  } else if (ws_size >= WS_SPLIT_BYTES) {
    hipFuncSetAttribute((const void*)(cfc5<0, 0>),
                        hipFuncAttributeMaxDynamicSharedMemorySize, DYN_SMEM);
    cfc5<0, 0><<<Bn, NT1, DYN_SMEM, stream>>>(x, ts, bb, bf1, bf2, bta, btb, bo, ws, out);
    hipFuncSetAttribute((const void*)ygemm,
                        hipFuncAttributeMaxDynamicSharedMemorySize, SMEMY);
    ygemm<<<(Bn * Sn) / 256, 256, SMEMY, stream>>>(ws, bo, out);
  } else {
    hipFuncSetAttribute((const void*)(cfc5<0, 1>),
                        hipFuncAttributeMaxDynamicSharedMemorySize, DYN_SMEM);
    cfc5<0, 1><<<Bn, NT1, DYN_SMEM, stream>>>(x, ts, bb, bf1, bf2, bta, btb, bo, ws, out);
  }
}

// Round 9
// 4795.673 us; speedup vs baseline: 2.3264x; 2.3264x over previous
//
#include <hip/hip_runtime.h>

// B=128, S=1024, F_IN=128, H=256, BB=256, F_OUT=128
#define Bn   128
#define Sn   1024
#define FIN  128
#define Hn   256
#define FOUT 128
#define KBB  384
#define NT1  512

// ---- fallback cfc5 (round-5 best measured: 3980 us) ----
#define NR4 20
#define NL4 1
#define DYN_SMEM ((32 * 256 * 8 + NL4 * 1024 * 8) * 2)

// ---- pair-split cfc6: 2 WGs per row, 256 WGs = 256 CUs ----
// LDS per WG: Wb_h half 64 KB + NL6 W4 chunks (512 cols) 88 KB = 152 KB dyn.
// Streamed 21 chunks = 168 KB/step; PF6=12 reg-prefetched at loop top
// (asm-materialized at H start: 48 + ~50 working < 128-reg cap, no spill).
// Round-7 lesson: ACQ/REL agent atomics emit whole-L2 inv/wb per poll ->
// 10.9 ms. Round-8 lesson: relaxed atomic LOADS hit stale lines in the
// reader's own XCD L2 (mbox lines cached 2 steps ago) -> wrong results.
// Fix: RMW everywhere. RMWs execute at the coherence point (cross-XCD
// coherent by default, guide m20) with NO cache maintenance:
//   write = atomic_exchange, read = fetch_add(+0), poll = fetch_add(0u).
#define NL6 11
#define PF6 12
#define DYN6 ((16 * 256 * 8 + NL6 * 512 * 8) * 2)   // 155648 B

// packed weight layout in d_ws (halves):
//   Wb_p [48][256][8]  (chunks 0-15 = x-part, 16-47 = h-part)
//   W4_p [32][1024][8] (N = [ff1|ff2|ta|tb])
//   Wo_p [32][128][8]
//   hbuf [B*S*H] fp16 ; xc [B*S*BB] fp16 ; mbox fp32 ; cnt u32
#define WB_OFF 0
#define W4_OFF 98304
#define WO_OFF 360448
#define WS_HALVES 393216
#define HBUF_OFF WS_HALVES
#define XC_OFF (HBUF_OFF + (size_t)Bn * Sn * Hn)
#define WS_SPLIT_BYTES ((size_t)(WS_HALVES + (size_t)Bn * Sn * Hn) * 2)
#define WS_FULL_BYTES ((XC_OFF + (size_t)Bn * Sn * Hn) * 2)
#define MBOX_BYTE_OFF WS_FULL_BYTES
#define MBOX_FLOATS ((size_t)Bn * 2 * 2 * 256)          // [row][hf][buf][256]
#define CNT_BYTE_OFF (MBOX_BYTE_OFF + MBOX_FLOATS * 4)
#define WS_PAIR_BYTES (CNT_BYTE_OFF + 256 * 4)

typedef _Float16 h2 __attribute__((ext_vector_type(2)));
typedef _Float16 h8 __attribute__((ext_vector_type(8)));

__device__ __forceinline__ float dot2f(h2 a, h2 b, float c) {
#if __has_builtin(__builtin_amdgcn_fdot2)
  return __builtin_amdgcn_fdot2(a, b, c, false);   // v_dot2_f32_f16
#else
  return c + (float)a[0] * (float)b[0] + (float)a[1] * (float)b[1];
#endif
}
__device__ __forceinline__ void dot8_4(h8 v, h8 w, float& c0, float& c1, float& c2, float& c3) {
  h2 v0 = {v[0], v[1]}, v1 = {v[2], v[3]}, v2 = {v[4], v[5]}, v3 = {v[6], v[7]};
  h2 w0 = {w[0], w[1]}, w1 = {w[2], w[3]}, w2 = {w[4], w[5]}, w3 = {w[6], w[7]};
  c0 = dot2f(v0, w0, c0); c1 = dot2f(v1, w1, c1);
  c2 = dot2f(v2, w2, c2); c3 = dot2f(v3, w3, c3);
}

// fp32 -> fp16 packing (verified layout)
__global__ __launch_bounds__(256) void pack_w(
    const float* __restrict__ Wb, const float* __restrict__ W1,
    const float* __restrict__ W2, const float* __restrict__ W3,
    const float* __restrict__ W4, const float* __restrict__ Wo,
    _Float16* __restrict__ ws) {
  int p = blockIdx.x * 256 + threadIdx.x;
  if (p >= WS_HALVES) return;
  float v;
  if (p < W4_OFF) {                       // backbone [384,256] row-major
    int r = p & 7, j = (p >> 3) & 255;
    int k = ((p >> 11) << 3) | r;
    v = Wb[k * 256 + j];
  } else if (p < WO_OFF) {                // heads concat: N = [ff1|ff2|ta|tb]
    int q = p - W4_OFF;
    int r = q & 7, j = (q >> 3) & 1023;
    int k = ((q >> 13) << 3) | r;
    int jj = j & 255;
    const float* Ws = (j < 256) ? W1 : (j < 512) ? W2 : (j < 768) ? W3 : W4;
    v = Ws[k * 256 + jj];
  } else {                                // Wout [256,128]
    int q = p - WO_OFF;
    int r = q & 7, j = (q >> 3) & 127;
    int k = ((q >> 10) << 3) | r;
    v = Wo[k * 128 + j];
  }
  ws[p] = (_Float16)v;
}

__global__ void zcnt(unsigned* __restrict__ c) { c[threadIdx.x] = 0; }

// xc[r,j] = sum_k x[r,k] * Wb[k,j]  (k<128, non-recurrent x-part of Z)
__global__ __launch_bounds__(256) void xgemm(
    const float* __restrict__ x, const _Float16* __restrict__ ws,
    _Float16* __restrict__ xc) {
  __shared__ __align__(16) _Float16 sX[64 * 128];   // 16 KB
  const int tid = threadIdx.x;
  const size_t r0 = (size_t)blockIdx.x * 64;
  const float* xb = x + r0 * 128;
#pragma unroll
  for (int m = 0; m < 32; ++m)
    sX[m * 256 + tid] = (_Float16)xb[m * 256 + tid];
  const _Float16* gX = ws + WB_OFF + (size_t)tid * 8;   // chunks 0-15 = x-part
  h8 wx[16];
#pragma unroll
  for (int L = 0; L < 16; ++L) wx[L] = *(const h8*)(gX + (size_t)L * 2048);
  __syncthreads();
  for (int r = 0; r < 64; ++r) {
    float c0 = 0.f, c1 = 0.f, c2 = 0.f, c3 = 0.f;
#pragma unroll
    for (int L = 0; L < 16; ++L) {
      h8 v = *(const h8*)&sX[r * 128 + L * 8];          // broadcast
      dot8_4(v, wx[L], c0, c1, c2, c3);
    }
    xc[(r0 + r) * 256 + tid] = (_Float16)(c0 + c1 + c2 + c3);
  }
}

// Pair-split recurrent kernel. WG (row = blockIdx&127, hf = blockIdx>>7).
// Per step:  Z-partial over OWN h-half (Wb_h half LDS-resident)
//           -> exchange z-partials with partner (1 KB ping-pong mailbox,
//              pure-RMW protocol: coherent at L3, no cache maintenance)
//           -> full zf local -> heads for own 128 h-cols
//           -> own h-half locally (it IS the Z K-half: no h exchange).
// Ordering: __syncthreads drains vmcnt(0) per wave, so mbox RMWs are
// performed at L3 before tid0's counter RMW issues; reader's successful
// counter RMW therefore precedes coherent mbox RMW reads. Buffer reuse
// lag <= 1 (write buf[st&1] at st+2 only after observing c_pt >= st+2,
// which requires partner to have completed its step-st reads).
__global__ __launch_bounds__(NT1) void cfc6(
    const float* __restrict__ ts, const float* __restrict__ bb,
    const float* __restrict__ bf1, const float* __restrict__ bf2,
    const float* __restrict__ bta, const float* __restrict__ btb,
    _Float16* __restrict__ ws, unsigned* __restrict__ cnt,
    float* __restrict__ mbox) {
  __shared__ __align__(16) _Float16 hl[128];     // own h half
  __shared__ __align__(16) _Float16 zfs[Hn];     // full z (fp16)
  __shared__ float tsb[Sn];
  __shared__ float scrZ[256];
  __shared__ float scrH[384];
  extern __shared__ __align__(16) _Float16 dyn[];
  _Float16* sWbh = dyn;                  // [16][256][8] = 64 KB
  _Float16* sW4L = dyn + 16 * 256 * 8;   // [NL6][512][8] = 88 KB

  const int tid = threadIdx.x;
  const int row = blockIdx.x & 127;
  const int hf  = blockIdx.x >> 7;

  const _Float16* Wb_p = ws + WB_OFF;
  const _Float16* W4_p = ws + W4_OFF;
  _Float16* hbuf = ws + HBUF_OFF;
  const _Float16* xcp = ws + XC_OFF;
  const float* tsrow = ts + (size_t)row * Sn;

  const int jz = tid & 255, kq = tid >> 8;       // Z roles
  const int head = tid >> 7, jj = tid & 127;     // H roles
  const int jcol = head * 256 + hf * 128 + jj;   // packed W4 col
  const float bbj = (tid < 256) ? bb[tid] : 0.f;
  const float bH =
      (head == 0 ? bf1 : head == 1 ? bf2 : head == 2 ? bta : btb)[hf * 128 + jj];
  const _Float16* gH = W4_p + (size_t)jcol * 8;

  // ---- one-time staging ----
  {  // Wb_h rows for own h-half: chunks 16+hf*16 .. +16
    const h8* src = (const h8*)(Wb_p + (size_t)(16 + hf * 16) * 2048);
    h8* dst = (h8*)sWbh;
    for (int i = tid; i < 16 * 256; i += NT1) dst[i] = src[i];
  }
#pragma unroll
  for (int c = 0; c < NL6; ++c)                  // W4 chunks 0..NL6 (own cols)
    *(h8*)&sW4L[((size_t)c * 512 + tid) * 8] = *(const h8*)(gH + (size_t)c * 8192);
  for (int i = tid; i < Sn; i += NT1) tsb[i] = tsrow[i];
  if (tid < 128) hl[tid] = (_Float16)0.f;        // h0 = 0

  float* mb_me       = mbox + (size_t)(row * 2 + hf) * 512;        // [2][256]
  float* mb_pt       = mbox + (size_t)(row * 2 + (1 - hf)) * 512;
  unsigned* c_me = cnt + row * 2 + hf;
  unsigned* c_pt = cnt + row * 2 + (1 - hf);
  __syncthreads();

  for (unsigned st = 0; st < Sn; ++st) {
    // reg-prefetch of streamed W4 chunks: issued here, materialized at H
    h8 wpf[PF6];
#pragma unroll
    for (int c = 0; c < PF6; ++c)
      wpf[c] = *(const h8*)(gH + (size_t)(NL6 + c) * 8192);
    float xcv = 0.f;
    if (tid < 256) xcv = (float)xcp[((size_t)row * Sn + st) * 256 + tid];

    // ---- Z partial: own K-half (h-local), all 256 cols ----
    float a0 = 0.f, a1 = 0.f, a2 = 0.f, a3 = 0.f;
#pragma unroll
    for (int c = kq * 8; c < kq * 8 + 8; ++c) {
      h8 v = *(const h8*)&hl[c * 8];                       // broadcast
      h8 w = *(const h8*)&sWbh[((size_t)c * 256 + jz) * 8];
      dot8_4(v, w, a0, a1, a2, a3);
    }
    float zs = a0 + a1 + a2 + a3;
    if (kq) scrZ[jz] = zs;
    __syncthreads();                       // B1
    float zp = 0.f;
    if (tid < 256) {
      zp = zs + scrZ[tid];
      // RMW write: performed at coherence point, no cache side effects
      (void)__hip_atomic_exchange(&mb_me[(st & 1) * 256 + tid], zp,
                                  __ATOMIC_RELAXED, __HIP_MEMORY_SCOPE_AGENT);
    }
    __syncthreads();                       // B2: vmcnt(0) drained -> RMWs at L3
    if (tid == 0) {
      __hip_atomic_fetch_add(c_me, 1u, __ATOMIC_RELAXED, __HIP_MEMORY_SCOPE_AGENT);
      // RMW poll: reads the coherence point, never a stale local L2 line
      while (__hip_atomic_fetch_add(c_pt, 0u, __ATOMIC_RELAXED,
                                    __HIP_MEMORY_SCOPE_AGENT) <= st)
        __builtin_amdgcn_s_sleep(1);
    }
    __syncthreads();                       // B3: partner data published
    if (tid < 256) {
      // RMW read (+0): returns current value from the coherence point
      float pz = __hip_atomic_fetch_add(&mb_pt[(st & 1) * 256 + tid], 0.0f,
                                        __ATOMIC_RELAXED, __HIP_MEMORY_SCOPE_AGENT);
      zfs[tid] = (_Float16)tanhf(zp + pz + xcv + bbj);
    }
    __syncthreads();                       // B4: zf ready

    // ---- H: own col of [ff1|ff2|ta|tb], K=256 ----
    float s0 = 0.f, s1 = 0.f, s2 = 0.f, s3 = 0.f;
#pragma unroll 2
    for (int c = NL6 + PF6; c < 32; ++c) {               // streamed tail
      h8 v = *(const h8*)&zfs[c * 8];
      h8 w = *(const h8*)(gH + (size_t)c * 8192);
      dot8_4(v, w, s0, s1, s2, s3);
    }
    // materialize prefetched chunks here (loads stay issued at loop top;
    // 48 + ~50 working regs < 128 cap, so they live in VGPRs, not scratch)
#pragma unroll
    for (int c = 0; c < PF6; ++c) asm volatile("" : "+v"(wpf[c]));
#pragma unroll
    for (int c = 0; c < PF6; ++c) {                       // prefetched
      h8 v = *(const h8*)&zfs[(NL6 + c) * 8];
      dot8_4(v, wpf[c], s0, s1, s2, s3);
    }
    float b0 = 0.f, b1 = 0.f, b2 = 0.f, b3 = 0.f;
#pragma unroll
    for (int c = 0; c < NL6; ++c) {                       // LDS-resident
      h8 v = *(const h8*)&zfs[c * 8];
      h8 w = *(const h8*)&sW4L[((size_t)c * 512 + tid) * 8];
      dot8_4(v, w, b0, b1, b2, b3);
    }
    float g = (s0 + b0) + (s1 + b1) + (s2 + b2) + (s3 + b3) + bH;
    if (head) scrH[(head - 1) * 128 + jj] = g;
    __syncthreads();                       // B5
    if (head == 0) {
      float ff2 = scrH[jj], ta = scrH[128 + jj], tb = scrH[256 + jj];
      float tt = tsb[st];
      float sg = 1.f / (1.f + __expf(-(ta * tt + tb)));
      float hn = tanhf(g) * (1.f - sg) + sg * tanhf(ff2);
      hl[jj] = (_Float16)hn;
      hbuf[((size_t)row * Sn + st) * Hn + hf * 128 + jj] = (_Float16)hn;
    }
    __syncthreads();                       // B6: hl ready for next Z
  }
}

// ---- fallback: round-5 cfc5 (one WG per row) ----
template <int XC, int INLINE_Y>
__global__ __launch_bounds__(NT1, 2) void cfc5(
    const float* __restrict__ x, const float* __restrict__ ts,
    const float* __restrict__ bb, const float* __restrict__ bf1,
    const float* __restrict__ bf2, const float* __restrict__ bta,
    const float* __restrict__ btb, const float* __restrict__ bo,
    _Float16* __restrict__ ws, float* __restrict__ out) {
  __shared__ __align__(16) _Float16 xh[KBB];
  __shared__ __align__(16) _Float16 zf[Hn];
  __shared__ float tsb[Sn];
  __shared__ float scrZ[256];
  __shared__ float scrH[512];
  extern __shared__ __align__(16) _Float16 dyn[];
  _Float16* sWb  = dyn;                        // [32][256][8] = 128 KB (XC=1)
  _Float16* sW4L = dyn + 32 * 256 * 8;         // [NL4][1024][8] = 16 KB

  const int tid = threadIdx.x;
  const int b = blockIdx.x;
  const _Float16* Wb_p = ws + WB_OFF;
  const _Float16* W4_p = ws + W4_OFF;
  const _Float16* Wo_p = ws + WO_OFF;
  _Float16* hbuf = ws + HBUF_OFF;
  const _Float16* xcp = ws + XC_OFF;

  const float* xrow  = x  + (size_t)b * Sn * FIN;
  const float* tsrow = ts + (size_t)b * Sn;
  float*       orow  = out + (size_t)b * Sn * FOUT;

  const int jz = tid & 255, kz = tid >> 8;
  const float bbj = (tid < 256) ? bb[tid] : 0.f;
  const float bHA = (tid < 256) ? bf1[tid] : bf2[tid - 256];
  const float bHB = (tid < 256) ? bta[tid] : btb[tid - 256];
  const int jY = tid & 127, kqY = tid >> 7;
  const float boj = bo[jY];

  if (XC) {
    const h8* src = (const h8*)(Wb_p + (size_t)16 * 2048);
    h8* dst = (h8*)sWb;
    for (int i = tid; i < 8192; i += NT1) dst[i] = src[i];
  }
  {
    const h8* src = (const h8*)(W4_p + (size_t)NR4 * 8192);
    h8* dst = (h8*)sW4L;
    for (int i = tid; i < NL4 * 1024; i += NT1) dst[i] = src[i];
  }
  for (int i = tid; i < Sn; i += NT1) tsb[i] = tsrow[i];
  if (tid < 128) ((unsigned*)xh)[64 + tid] = 0;
  if (!XC && tid < 64) {
    float2 xv = *(const float2*)(xrow + 2 * tid);
    h2 p; p[0] = (_Float16)xv.x; p[1] = (_Float16)xv.y;
    *(h2*)&xh[2 * tid] = p;
  }

  const _Float16* gA = W4_p + (size_t)tid * 8;
  const _Float16* gB = W4_p + (size_t)(tid + 512) * 8;
  h8 wA[NR4], wBv[NR4];
#pragma unroll
  for (int c = 0; c < NR4; ++c) {
    wA[c]  = *(const h8*)(gA + (size_t)c * 8192);
    wBv[c] = *(const h8*)(gB + (size_t)c * 8192);
  }
#pragma unroll
  for (int c = 0; c < NR4; ++c) {
    asm volatile("" : "+v"(wA[c]));
    asm volatile("" : "+v"(wBv[c]));
  }
  __syncthreads();

  for (int st = 0; st < Sn; ++st) {
    float xcv = 0.f;
    if (XC && tid < 256)
      xcv = (float)xcp[((size_t)b * Sn + st) * 256 + tid];
    float2 xv; xv.x = 0.f; xv.y = 0.f;
    if (!XC && tid >= 448 && st + 1 < Sn)
      xv = *(const float2*)(xrow + (size_t)(st + 1) * FIN + 2 * (tid - 448));

    float a0 = 0.f, a1 = 0.f, a2 = 0.f, a3 = 0.f;
    if (XC) {
#pragma unroll 4
      for (int c = 0; c < 16; ++c) {
        int kc = kz * 16 + c;
        h8 v = *(const h8*)&xh[128 + kc * 8];
        h8 w = *(const h8*)&sWb[((size_t)kc * 256 + jz) * 8];
        dot8_4(v, w, a0, a1, a2, a3);
      }
    } else {
      const _Float16* gZ = Wb_p + ((size_t)(kz * 24) * 256 + jz) * 8;
#pragma unroll 4
      for (int c = 0; c < 24; ++c) {
        h8 v = *(const h8*)&xh[(kz * 24 + c) * 8];
        h8 w = *(const h8*)(gZ + (size_t)c * 2048);
        dot8_4(v, w, a0, a1, a2, a3);
      }
    }
    float zs = a0 + a1 + a2 + a3;
    if (kz) scrZ[jz] = zs;
    __syncthreads();
    if (tid < 256) {
      float zp = zs + scrZ[tid] + bbj;
      if (XC) zp += xcv;
      zf[tid] = (_Float16)tanhf(zp);
    }
    if (!XC && tid >= 448 && st + 1 < Sn) {
      h2 p; p[0] = (_Float16)xv.x; p[1] = (_Float16)xv.y;
      *(h2*)&xh[2 * (tid - 448)] = p;
    }
    __syncthreads();

    float hA0 = 0.f, hA1 = 0.f, hA2 = 0.f, hA3 = 0.f;
    float hB0 = 0.f, hB1 = 0.f, hB2 = 0.f, hB3 = 0.f;
#pragma unroll 2
    for (int c = NR4 + NL4; c < 32; ++c) {
      h8 v  = *(const h8*)&zf[c * 8];
      h8 wa = *(const h8*)(gA + (size_t)c * 8192);
      h8 wb = *(const h8*)(gB + (size_t)c * 8192);
      dot8_4(v, wa, hA0, hA1, hA2, hA3);
      dot8_4(v, wb, hB0, hB1, hB2, hB3);
    }
#pragma unroll
    for (int c = 0; c < NR4; ++c) {
      h8 v = *(const h8*)&zf[c * 8];
      dot8_4(v, wA[c],  hA0, hA1, hA2, hA3);
      dot8_4(v, wBv[c], hB0, hB1, hB2, hB3);
    }
#pragma unroll
    for (int l = 0; l < NL4; ++l) {
      h8 v  = *(const h8*)&zf[(NR4 + l) * 8];
      h8 wa = *(const h8*)&sW4L[((size_t)l * 1024 + tid) * 8];
      h8 wb = *(const h8*)&sW4L[((size_t)l * 1024 + tid + 512) * 8];
      dot8_4(v, wa, hA0, hA1, hA2, hA3);
      dot8_4(v, wb, hB0, hB1, hB2, hB3);
    }
    float gAv = hA0 + hA1 + hA2 + hA3 + bHA;
    float gBv = hB0 + hB1 + hB2 + hB3 + bHB;
    if (tid >= 256) {
      scrH[tid - 256]       = gAv;
      scrH[256 + tid - 256] = gBv;
    }
    __syncthreads();
    if (tid < 256) {
      float ff2v = scrH[tid], tbv = scrH[256 + tid];
      float tt = tsb[st];
      float sg = 1.f / (1.f + __expf(-(gBv * tt + tbv)));
      float hn = tanhf(gAv) * (1.f - sg) + sg * tanhf(ff2v);
      xh[128 + tid] = (_Float16)hn;
      if (!INLINE_Y)
        hbuf[((size_t)b * Sn + st) * Hn + tid] = (_Float16)hn;
    }
    __syncthreads();

    if (INLINE_Y) {
      const _Float16* gY = Wo_p + ((size_t)(kqY * 8) * 128 + jY) * 8;
      float y0 = 0.f, y1 = 0.f, y2 = 0.f, y3 = 0.f;
#pragma unroll
      for (int c = 0; c < 8; ++c) {
        h8 v = *(const h8*)&xh[128 + (kqY * 8 + c) * 8];
        h8 w = *(const h8*)(gY + (size_t)c * 1024);
        dot8_4(v, w, y0, y1, y2, y3);
      }
      float ysv = y0 + y1 + y2 + y3;
      if (kqY) scrH[(kqY - 1) * 128 + jY] = ysv;
      __syncthreads();
      if (kqY == 0) {
        float y = ysv + boj + scrH[jY] + scrH[128 + jY] + scrH[256 + jY];
        orow[(size_t)st * FOUT + jY] = y;
      }
    }
  }
}

// Phase 2 (split path): y[BS,128] = h[BS,256] @ Wout + bo
#define SMEMY (65536 + 4096)
extern "C" __global__ __launch_bounds__(256, 4)
void ygemm(const _Float16* __restrict__ ws, const float* __restrict__ bo,
           float* __restrict__ out) {
  extern __shared__ char ysm[];
  _Float16* sWo = (_Float16*)ysm;            // 32768 halves
  _Float16* sH  = (_Float16*)(ysm + 65536);  // 8 x 256 halves
  const int tid = threadIdx.x;
  { const uint4* g = (const uint4*)(ws + WO_OFF);
    uint4* l = (uint4*)sWo;
#pragma unroll
    for (int i = 0; i < 16; ++i) l[tid + 256 * i] = g[tid + 256 * i]; }
  const _Float16* hb = ws + HBUF_OFF;
  const int row0 = blockIdx.x * 256;
  const int j = tid & 127, rh = tid >> 7;
  const float boj = bo[j];
  for (int it = 0; it < 32; ++it) {
    const int rbase = row0 + it * 8;
    __syncthreads();
    ((uint4*)sH)[tid] = ((const uint4*)(hb + (size_t)rbase * 256))[tid];
    __syncthreads();
#pragma unroll
    for (int rr = rh; rr < 8; rr += 2) {
      float y0 = 0.f, y1 = 0.f, y2 = 0.f, y3 = 0.f;
#pragma unroll 4
      for (int c = 0; c < 32; ++c) {
        h8 v = *(const h8*)&sH[rr * 256 + c * 8];
        h8 w = *(const h8*)&sWo[((size_t)c * 128 + j) * 8];
        dot8_4(v, w, y0, y1, y2, y3);
      }
      out[(size_t)(rbase + rr) * 128 + j] = y0 + y1 + y2 + y3 + boj;
    }
  }
}

extern "C" void kernel_launch(void* const* d_in, const int* in_sizes, int n_in,
                              void* d_out, int out_size, void* d_ws, size_t ws_size,
                              hipStream_t stream) {
  const float* x   = (const float*)d_in[0];
  const float* ts  = (const float*)d_in[1];
  const float* Wb  = (const float*)d_in[2];
  const float* bb  = (const float*)d_in[3];
  const float* W1  = (const float*)d_in[4];
  const float* bf1 = (const float*)d_in[5];
  const float* W2  = (const float*)d_in[6];
  const float* bf2 = (const float*)d_in[7];
  const float* W3  = (const float*)d_in[8];
  const float* bta = (const float*)d_in[9];
  const float* W4  = (const float*)d_in[10];
  const float* btb = (const float*)d_in[11];
  const float* Wo  = (const float*)d_in[12];
  const float* bo  = (const float*)d_in[13];
  float* out = (float*)d_out;
  _Float16* ws = (_Float16*)d_ws;

  pack_w<<<WS_HALVES / 256, 256, 0, stream>>>(Wb, W1, W2, W3, W4, Wo, ws);

  if (ws_size >= WS_PAIR_BYTES) {
    zcnt<<<1, 256, 0, stream>>>((unsigned*)((char*)d_ws + CNT_BYTE_OFF));
    xgemm<<<(Bn * Sn) / 64, 256, 0, stream>>>(x, ws, ws + XC_OFF);
    hipFuncSetAttribute((const void*)cfc6,
                        hipFuncAttributeMaxDynamicSharedMemorySize, DYN6);
    cfc6<<<2 * Bn, NT1, DYN6, stream>>>(
        ts, bb, bf1, bf2, bta, btb, ws,
        (unsigned*)((char*)d_ws + CNT_BYTE_OFF),
        (float*)((char*)d_ws + MBOX_BYTE_OFF));
    hipFuncSetAttribute((const void*)ygemm,
                        hipFuncAttributeMaxDynamicSharedMemorySize, SMEMY);
    ygemm<<<(Bn * Sn) / 256, 256, SMEMY, stream>>>(ws, bo, out);
  } else if (ws_size >= WS_FULL_BYTES) {
    xgemm<<<(Bn * Sn) / 64, 256, 0, stream>>>(x, ws, ws + XC_OFF);
    hipFuncSetAttribute((const void*)(cfc5<1, 0>),
                        hipFuncAttributeMaxDynamicSharedMemorySize, DYN_SMEM);
    cfc5<1, 0><<<Bn, NT1, DYN_SMEM, stream>>>(x, ts, bb, bf1, bf2, bta, btb, bo, ws, out);
    hipFuncSetAttribute((const void*)ygemm,
                        hipFuncAttributeMaxDynamicSharedMemorySize, SMEMY);
    ygemm<<<(Bn * Sn) / 256, 256, SMEMY, stream>>>(ws, bo, out);
  } else if (ws_size >= WS_SPLIT_BYTES) {
    hipFuncSetAttribute((const void*)(cfc5<0, 0>),
                        hipFuncAttributeMaxDynamicSharedMemorySize, DYN_SMEM);
    cfc5<0, 0><<<Bn, NT1, DYN_SMEM, stream>>>(x, ts, bb, bf1, bf2, bta, btb, bo, ws, out);
    hipFuncSetAttribute((const void*)ygemm,
                        hipFuncAttributeMaxDynamicSharedMemorySize, SMEMY);
    ygemm<<<(Bn * Sn) / 256, 256, SMEMY, stream>>>(ws, bo, out);
  } else {
    hipFuncSetAttribute((const void*)(cfc5<0, 1>),
                        hipFuncAttributeMaxDynamicSharedMemorySize, DYN_SMEM);
    cfc5<0, 1><<<Bn, NT1, DYN_SMEM, stream>>>(x, ts, bb, bf1, bf2, bta, btb, bo, ws, out);
  }
}

// Round 10
// 4239.440 us; speedup vs baseline: 2.6316x; 1.1312x over previous
//
#include <hip/hip_runtime.h>

// B=128, S=1024, F_IN=128, H=256, BB=256, F_OUT=128
#define Bn   128
#define Sn   1024
#define FIN  128
#define Hn   256
#define FOUT 128
#define KBB  384
#define NT1  512

// ---- fallback cfc5 (round-5 best measured: 3980 us) ----
#define NR4 20
#define NL4 1
#define DYN_SMEM ((32 * 256 * 8 + NL4 * 1024 * 8) * 2)

// ---- pair-split cfc6: 2 WGs per row, 256 WGs = 256 CUs ----
// LDS per WG: Wb_h half 64 KB + NL6 W4 chunks (512 cols) 88 KB = 152 KB dyn.
// Streamed 21 chunks = 168 KB/step; PF6=16 reg-prefetched at loop top
// (issued before Z, asm-materialized at H: in flight across the exchange).
// Sync protocol history:
//   R7: ACQ/REL agent atomics -> whole-L2 inv/wb per poll -> 10.9 ms storm.
//   R8: relaxed atomic LOADS -> stale XCD-L2 mailbox lines -> WRONG.
//   R9: pure-RMW (exch / fetch_add(0) / counter) -> correct, 4.7 ms; ~2.7
//       us/step was sync: 4-5 serial L3 RTTs + 6 barriers.
//   R10 (this): tag-embedded u64 words. write = atomic_exchange of
//       (st+1)<<32 | f32bits; read = per-lane fetch_add(0) poll until tag
//       matches. No counters, no B2/B3 barriers, per-lane completion.
//       Lag<=1 backpressure is structural: A overwrites buf[st&1] at st+2
//       only after observing B's tag st+2, which B wrote after (program
//       order) consuming A's step-st data.
#define NL6 11
#define PF6 16
#define DYN6 ((16 * 256 * 8 + NL6 * 512 * 8) * 2)   // 155648 B

// packed weight layout in d_ws (halves):
//   Wb_p [48][256][8]  (chunks 0-15 = x-part, 16-47 = h-part)
//   W4_p [32][1024][8] (N = [ff1|ff2|ta|tb])
//   Wo_p [32][128][8]
//   hbuf [B*S*H] fp16 ; xc [B*S*BB] fp16 ; mbox u64 (tag|value)
#define WB_OFF 0
#define W4_OFF 98304
#define WO_OFF 360448
#define WS_HALVES 393216
#define HBUF_OFF WS_HALVES
#define XC_OFF (HBUF_OFF + (size_t)Bn * Sn * Hn)
#define WS_SPLIT_BYTES ((size_t)(WS_HALVES + (size_t)Bn * Sn * Hn) * 2)
#define WS_FULL_BYTES ((XC_OFF + (size_t)Bn * Sn * Hn) * 2)
#define MBOX_BYTE_OFF WS_FULL_BYTES
#define MBOX_WORDS ((size_t)Bn * 2 * 2 * 256)           // [row][hf][buf][256] u64
#define WS_PAIR_BYTES (MBOX_BYTE_OFF + MBOX_WORDS * 8)

typedef _Float16 h2 __attribute__((ext_vector_type(2)));
typedef _Float16 h8 __attribute__((ext_vector_type(8)));

__device__ __forceinline__ float dot2f(h2 a, h2 b, float c) {
#if __has_builtin(__builtin_amdgcn_fdot2)
  return __builtin_amdgcn_fdot2(a, b, c, false);   // v_dot2_f32_f16
#else
  return c + (float)a[0] * (float)b[0] + (float)a[1] * (float)b[1];
#endif
}
__device__ __forceinline__ void dot8_4(h8 v, h8 w, float& c0, float& c1, float& c2, float& c3) {
  h2 v0 = {v[0], v[1]}, v1 = {v[2], v[3]}, v2 = {v[4], v[5]}, v3 = {v[6], v[7]};
  h2 w0 = {w[0], w[1]}, w1 = {w[2], w[3]}, w2 = {w[4], w[5]}, w3 = {w[6], w[7]};
  c0 = dot2f(v0, w0, c0); c1 = dot2f(v1, w1, c1);
  c2 = dot2f(v2, w2, c2); c3 = dot2f(v3, w3, c3);
}

// fp32 -> fp16 packing (verified layout)
__global__ __launch_bounds__(256) void pack_w(
    const float* __restrict__ Wb, const float* __restrict__ W1,
    const float* __restrict__ W2, const float* __restrict__ W3,
    const float* __restrict__ W4, const float* __restrict__ Wo,
    _Float16* __restrict__ ws) {
  int p = blockIdx.x * 256 + threadIdx.x;
  if (p >= WS_HALVES) return;
  float v;
  if (p < W4_OFF) {                       // backbone [384,256] row-major
    int r = p & 7, j = (p >> 3) & 255;
    int k = ((p >> 11) << 3) | r;
    v = Wb[k * 256 + j];
  } else if (p < WO_OFF) {                // heads concat: N = [ff1|ff2|ta|tb]
    int q = p - W4_OFF;
    int r = q & 7, j = (q >> 3) & 1023;
    int k = ((q >> 13) << 3) | r;
    int jj = j & 255;
    const float* Ws = (j < 256) ? W1 : (j < 512) ? W2 : (j < 768) ? W3 : W4;
    v = Ws[k * 256 + jj];
  } else {                                // Wout [256,128]
    int q = p - WO_OFF;
    int r = q & 7, j = (q >> 3) & 127;
    int k = ((q >> 10) << 3) | r;
    v = Wo[k * 128 + j];
  }
  ws[p] = (_Float16)v;
}

// zero the tag-mailbox (stale tags from a previous launch exactly alias the
// current launch's expected sequence -- must clear every launch)
__global__ void zmbox(unsigned long long* __restrict__ m) {
  m[(size_t)blockIdx.x * 256 + threadIdx.x] = 0ull;
}

// xc[r,j] = sum_k x[r,k] * Wb[k,j]  (k<128, non-recurrent x-part of Z)
__global__ __launch_bounds__(256) void xgemm(
    const float* __restrict__ x, const _Float16* __restrict__ ws,
    _Float16* __restrict__ xc) {
  __shared__ __align__(16) _Float16 sX[64 * 128];   // 16 KB
  const int tid = threadIdx.x;
  const size_t r0 = (size_t)blockIdx.x * 64;
  const float* xb = x + r0 * 128;
#pragma unroll
  for (int m = 0; m < 32; ++m)
    sX[m * 256 + tid] = (_Float16)xb[m * 256 + tid];
  const _Float16* gX = ws + WB_OFF + (size_t)tid * 8;   // chunks 0-15 = x-part
  h8 wx[16];
#pragma unroll
  for (int L = 0; L < 16; ++L) wx[L] = *(const h8*)(gX + (size_t)L * 2048);
  __syncthreads();
  for (int r = 0; r < 64; ++r) {
    float c0 = 0.f, c1 = 0.f, c2 = 0.f, c3 = 0.f;
#pragma unroll
    for (int L = 0; L < 16; ++L) {
      h8 v = *(const h8*)&sX[r * 128 + L * 8];          // broadcast
      dot8_4(v, wx[L], c0, c1, c2, c3);
    }
    xc[(r0 + r) * 256 + tid] = (_Float16)(c0 + c1 + c2 + c3);
  }
}

// Pair-split recurrent kernel. WG (row = blockIdx&127, hf = blockIdx>>7).
// Per step:  Z-partial over OWN h-half (Wb_h half LDS-resident)
//           -> tag-word exchange with partner (u64 RMW, per-lane poll)
//           -> full zf local -> heads for own 128 h-cols
//           -> own h-half locally (it IS the Z K-half: no h exchange).
// Memory-order argument (all RMW, relaxed, agent scope): RMWs execute at
// the coherence point; same-lane RMWs are ordered by the data dependence
// (poll result consumed before next RMW issues). See tag-protocol proof in
// the header comment.
__global__ __launch_bounds__(NT1) void cfc6(
    const float* __restrict__ ts, const float* __restrict__ bb,
    const float* __restrict__ bf1, const float* __restrict__ bf2,
    const float* __restrict__ bta, const float* __restrict__ btb,
    _Float16* __restrict__ ws, unsigned long long* __restrict__ mbox) {
  __shared__ __align__(16) _Float16 hl[128];     // own h half
  __shared__ __align__(16) _Float16 zfs[Hn];     // full z (fp16)
  __shared__ float tsb[Sn];
  __shared__ float scrZ[256];
  __shared__ float scrH[384];
  extern __shared__ __align__(16) _Float16 dyn[];
  _Float16* sWbh = dyn;                  // [16][256][8] = 64 KB
  _Float16* sW4L = dyn + 16 * 256 * 8;   // [NL6][512][8] = 88 KB

  const int tid = threadIdx.x;
  const int row = blockIdx.x & 127;
  const int hf  = blockIdx.x >> 7;

  const _Float16* Wb_p = ws + WB_OFF;
  const _Float16* W4_p = ws + W4_OFF;
  _Float16* hbuf = ws + HBUF_OFF;
  const _Float16* xcp = ws + XC_OFF;
  const float* tsrow = ts + (size_t)row * Sn;

  const int jz = tid & 255, kq = tid >> 8;       // Z roles
  const int head = tid >> 7, jj = tid & 127;     // H roles
  const int jcol = head * 256 + hf * 128 + jj;   // packed W4 col
  const float bbj = (tid < 256) ? bb[tid] : 0.f;
  const float bH =
      (head == 0 ? bf1 : head == 1 ? bf2 : head == 2 ? bta : btb)[hf * 128 + jj];
  const _Float16* gH = W4_p + (size_t)jcol * 8;

  // ---- one-time staging ----
  {  // Wb_h rows for own h-half: chunks 16+hf*16 .. +16
    const h8* src = (const h8*)(Wb_p + (size_t)(16 + hf * 16) * 2048);
    h8* dst = (h8*)sWbh;
    for (int i = tid; i < 16 * 256; i += NT1) dst[i] = src[i];
  }
#pragma unroll
  for (int c = 0; c < NL6; ++c)                  // W4 chunks 0..NL6 (own cols)
    *(h8*)&sW4L[((size_t)c * 512 + tid) * 8] = *(const h8*)(gH + (size_t)c * 8192);
  for (int i = tid; i < Sn; i += NT1) tsb[i] = tsrow[i];
  if (tid < 128) hl[tid] = (_Float16)0.f;        // h0 = 0

  unsigned long long* mb_me = mbox + (size_t)(row * 2 + hf) * 512;       // [2][256]
  unsigned long long* mb_pt = mbox + (size_t)(row * 2 + (1 - hf)) * 512;
  __syncthreads();

  for (unsigned st = 0; st < Sn; ++st) {
    // reg-prefetch of streamed W4 chunks: issued here, in flight across
    // Z + exchange; materialized at H (asm) so they stay in VGPRs.
    h8 wpf[PF6];
#pragma unroll
    for (int c = 0; c < PF6; ++c)
      wpf[c] = *(const h8*)(gH + (size_t)(NL6 + c) * 8192);
    float xcv = 0.f;
    if (tid < 256) xcv = (float)xcp[((size_t)row * Sn + st) * 256 + tid];

    // ---- Z partial: own K-half (h-local), all 256 cols ----
    float a0 = 0.f, a1 = 0.f, a2 = 0.f, a3 = 0.f;
#pragma unroll
    for (int c = kq * 8; c < kq * 8 + 8; ++c) {
      h8 v = *(const h8*)&hl[c * 8];                       // broadcast
      h8 w = *(const h8*)&sWbh[((size_t)c * 256 + jz) * 8];
      dot8_4(v, w, a0, a1, a2, a3);
    }
    float zs = a0 + a1 + a2 + a3;
    if (kq) scrZ[jz] = zs;
    __syncthreads();                       // B1: scrZ ready
    if (tid < 256) {
      float zp = zs + scrZ[tid];
      // publish own partial: (tag = st+1) | f32 bits, single RMW
      unsigned long long w =
          ((unsigned long long)(st + 1) << 32) | (unsigned long long)__float_as_uint(zp);
      (void)__hip_atomic_exchange(&mb_me[(st & 1) * 256 + tid], w,
                                  __ATOMIC_RELAXED, __HIP_MEMORY_SCOPE_AGENT);
      // per-lane poll of partner's word (RMW: always coherence-point value)
      unsigned long long r;
      do {
        r = __hip_atomic_fetch_add(&mb_pt[(st & 1) * 256 + tid], 0ull,
                                   __ATOMIC_RELAXED, __HIP_MEMORY_SCOPE_AGENT);
      } while ((unsigned)(r >> 32) != st + 1);
      float pz = __uint_as_float((unsigned)r);
      zfs[tid] = (_Float16)tanhf(zp + pz + xcv + bbj);
    }
    __syncthreads();                       // B4: zf ready

    // ---- H: own col of [ff1|ff2|ta|tb], K=256 ----
    float s0 = 0.f, s1 = 0.f, s2 = 0.f, s3 = 0.f;
#pragma unroll 2
    for (int c = NL6 + PF6; c < 32; ++c) {               // streamed tail (5)
      h8 v = *(const h8*)&zfs[c * 8];
      h8 w = *(const h8*)(gH + (size_t)c * 8192);
      dot8_4(v, w, s0, s1, s2, s3);
    }
    // materialize prefetched chunks (64 + ~40 working < 128 cap: no spill)
#pragma unroll
    for (int c = 0; c < PF6; ++c) asm volatile("" : "+v"(wpf[c]));
#pragma unroll
    for (int c = 0; c < PF6; ++c) {                       // prefetched
      h8 v = *(const h8*)&zfs[(NL6 + c) * 8];
      dot8_4(v, wpf[c], s0, s1, s2, s3);
    }
    float b0 = 0.f, b1 = 0.f, b2 = 0.f, b3 = 0.f;
#pragma unroll
    for (int c = 0; c < NL6; ++c) {                       // LDS-resident
      h8 v = *(const h8*)&zfs[c * 8];
      h8 w = *(const h8*)&sW4L[((size_t)c * 512 + tid) * 8];
      dot8_4(v, w, b0, b1, b2, b3);
    }
    float g = (s0 + b0) + (s1 + b1) + (s2 + b2) + (s3 + b3) + bH;
    if (head) scrH[(head - 1) * 128 + jj] = g;
    __syncthreads();                       // B5
    if (head == 0) {
      float ff2 = scrH[jj], ta = scrH[128 + jj], tb = scrH[256 + jj];
      float tt = tsb[st];
      float sg = 1.f / (1.f + __expf(-(ta * tt + tb)));
      float hn = tanhf(g) * (1.f - sg) + sg * tanhf(ff2);
      hl[jj] = (_Float16)hn;
      hbuf[((size_t)row * Sn + st) * Hn + hf * 128 + jj] = (_Float16)hn;
    }
    __syncthreads();                       // B6: hl ready for next Z
  }
}

// ---- fallback: round-5 cfc5 (one WG per row) ----
template <int XC, int INLINE_Y>
__global__ __launch_bounds__(NT1, 2) void cfc5(
    const float* __restrict__ x, const float* __restrict__ ts,
    const float* __restrict__ bb, const float* __restrict__ bf1,
    const float* __restrict__ bf2, const float* __restrict__ bta,
    const float* __restrict__ btb, const float* __restrict__ bo,
    _Float16* __restrict__ ws, float* __restrict__ out) {
  __shared__ __align__(16) _Float16 xh[KBB];
  __shared__ __align__(16) _Float16 zf[Hn];
  __shared__ float tsb[Sn];
  __shared__ float scrZ[256];
  __shared__ float scrH[512];
  extern __shared__ __align__(16) _Float16 dyn[];
  _Float16* sWb  = dyn;                        // [32][256][8] = 128 KB (XC=1)
  _Float16* sW4L = dyn + 32 * 256 * 8;         // [NL4][1024][8] = 16 KB

  const int tid = threadIdx.x;
  const int b = blockIdx.x;
  const _Float16* Wb_p = ws + WB_OFF;
  const _Float16* W4_p = ws + W4_OFF;
  const _Float16* Wo_p = ws + WO_OFF;
  _Float16* hbuf = ws + HBUF_OFF;
  const _Float16* xcp = ws + XC_OFF;

  const float* xrow  = x  + (size_t)b * Sn * FIN;
  const float* tsrow = ts + (size_t)b * Sn;
  float*       orow  = out + (size_t)b * Sn * FOUT;

  const int jz = tid & 255, kz = tid >> 8;
  const float bbj = (tid < 256) ? bb[tid] : 0.f;
  const float bHA = (tid < 256) ? bf1[tid] : bf2[tid - 256];
  const float bHB = (tid < 256) ? bta[tid] : btb[tid - 256];
  const int jY = tid & 127, kqY = tid >> 7;
  const float boj = bo[jY];

  if (XC) {
    const h8* src = (const h8*)(Wb_p + (size_t)16 * 2048);
    h8* dst = (h8*)sWb;
    for (int i = tid; i < 8192; i += NT1) dst[i] = src[i];
  }
  {
    const h8* src = (const h8*)(W4_p + (size_t)NR4 * 8192);
    h8* dst = (h8*)sW4L;
    for (int i = tid; i < NL4 * 1024; i += NT1) dst[i] = src[i];
  }
  for (int i = tid; i < Sn; i += NT1) tsb[i] = tsrow[i];
  if (tid < 128) ((unsigned*)xh)[64 + tid] = 0;
  if (!XC && tid < 64) {
    float2 xv = *(const float2*)(xrow + 2 * tid);
    h2 p; p[0] = (_Float16)xv.x; p[1] = (_Float16)xv.y;
    *(h2*)&xh[2 * tid] = p;
  }

  const _Float16* gA = W4_p + (size_t)tid * 8;
  const _Float16* gB = W4_p + (size_t)(tid + 512) * 8;
  h8 wA[NR4], wBv[NR4];
#pragma unroll
  for (int c = 0; c < NR4; ++c) {
    wA[c]  = *(const h8*)(gA + (size_t)c * 8192);
    wBv[c] = *(const h8*)(gB + (size_t)c * 8192);
  }
#pragma unroll
  for (int c = 0; c < NR4; ++c) {
    asm volatile("" : "+v"(wA[c]));
    asm volatile("" : "+v"(wBv[c]));
  }
  __syncthreads();

  for (int st = 0; st < Sn; ++st) {
    float xcv = 0.f;
    if (XC && tid < 256)
      xcv = (float)xcp[((size_t)b * Sn + st) * 256 + tid];
    float2 xv; xv.x = 0.f; xv.y = 0.f;
    if (!XC && tid >= 448 && st + 1 < Sn)
      xv = *(const float2*)(xrow + (size_t)(st + 1) * FIN + 2 * (tid - 448));

    float a0 = 0.f, a1 = 0.f, a2 = 0.f, a3 = 0.f;
    if (XC) {
#pragma unroll 4
      for (int c = 0; c < 16; ++c) {
        int kc = kz * 16 + c;
        h8 v = *(const h8*)&xh[128 + kc * 8];
        h8 w = *(const h8*)&sWb[((size_t)kc * 256 + jz) * 8];
        dot8_4(v, w, a0, a1, a2, a3);
      }
    } else {
      const _Float16* gZ = Wb_p + ((size_t)(kz * 24) * 256 + jz) * 8;
#pragma unroll 4
      for (int c = 0; c < 24; ++c) {
        h8 v = *(const h8*)&xh[(kz * 24 + c) * 8];
        h8 w = *(const h8*)(gZ + (size_t)c * 2048);
        dot8_4(v, w, a0, a1, a2, a3);
      }
    }
    float zs = a0 + a1 + a2 + a3;
    if (kz) scrZ[jz] = zs;
    __syncthreads();
    if (tid < 256) {
      float zp = zs + scrZ[tid] + bbj;
      if (XC) zp += xcv;
      zf[tid] = (_Float16)tanhf(zp);
    }
    if (!XC && tid >= 448 && st + 1 < Sn) {
      h2 p; p[0] = (_Float16)xv.x; p[1] = (_Float16)xv.y;
      *(h2*)&xh[2 * (tid - 448)] = p;
    }
    __syncthreads();

    float hA0 = 0.f, hA1 = 0.f, hA2 = 0.f, hA3 = 0.f;
    float hB0 = 0.f, hB1 = 0.f, hB2 = 0.f, hB3 = 0.f;
#pragma unroll 2
    for (int c = NR4 + NL4; c < 32; ++c) {
      h8 v  = *(const h8*)&zf[c * 8];
      h8 wa = *(const h8*)(gA + (size_t)c * 8192);
      h8 wb = *(const h8*)(gB + (size_t)c * 8192);
      dot8_4(v, wa, hA0, hA1, hA2, hA3);
      dot8_4(v, wb, hB0, hB1, hB2, hB3);
    }
#pragma unroll
    for (int c = 0; c < NR4; ++c) {
      h8 v = *(const h8*)&zf[c * 8];
      dot8_4(v, wA[c],  hA0, hA1, hA2, hA3);
      dot8_4(v, wBv[c], hB0, hB1, hB2, hB3);
    }
#pragma unroll
    for (int l = 0; l < NL4; ++l) {
      h8 v  = *(const h8*)&zf[(NR4 + l) * 8];
      h8 wa = *(const h8*)&sW4L[((size_t)l * 1024 + tid) * 8];
      h8 wb = *(const h8*)&sW4L[((size_t)l * 1024 + tid + 512) * 8];
      dot8_4(v, wa, hA0, hA1, hA2, hA3);
      dot8_4(v, wb, hB0, hB1, hB2, hB3);
    }
    float gAv = hA0 + hA1 + hA2 + hA3 + bHA;
    float gBv = hB0 + hB1 + hB2 + hB3 + bHB;
    if (tid >= 256) {
      scrH[tid - 256]       = gAv;
      scrH[256 + tid - 256] = gBv;
    }
    __syncthreads();
    if (tid < 256) {
      float ff2v = scrH[tid], tbv = scrH[256 + tid];
      float tt = tsb[st];
      float sg = 1.f / (1.f + __expf(-(gBv * tt + tbv)));
      float hn = tanhf(gAv) * (1.f - sg) + sg * tanhf(ff2v);
      xh[128 + tid] = (_Float16)hn;
      if (!INLINE_Y)
        hbuf[((size_t)b * Sn + st) * Hn + tid] = (_Float16)hn;
    }
    __syncthreads();

    if (INLINE_Y) {
      const _Float16* gY = Wo_p + ((size_t)(kqY * 8) * 128 + jY) * 8;
      float y0 = 0.f, y1 = 0.f, y2 = 0.f, y3 = 0.f;
#pragma unroll
      for (int c = 0; c < 8; ++c) {
        h8 v = *(const h8*)&xh[128 + (kqY * 8 + c) * 8];
        h8 w = *(const h8*)(gY + (size_t)c * 1024);
        dot8_4(v, w, y0, y1, y2, y3);
      }
      float ysv = y0 + y1 + y2 + y3;
      if (kqY) scrH[(kqY - 1) * 128 + jY] = ysv;
      __syncthreads();
      if (kqY == 0) {
        float y = ysv + boj + scrH[jY] + scrH[128 + jY] + scrH[256 + jY];
        orow[(size_t)st * FOUT + jY] = y;
      }
    }
  }
}

// Phase 2 (split path): y[BS,128] = h[BS,256] @ Wout + bo
#define SMEMY (65536 + 4096)
extern "C" __global__ __launch_bounds__(256, 4)
void ygemm(const _Float16* __restrict__ ws, const float* __restrict__ bo,
           float* __restrict__ out) {
  extern __shared__ char ysm[];
  _Float16* sWo = (_Float16*)ysm;            // 32768 halves
  _Float16* sH  = (_Float16*)(ysm + 65536);  // 8 x 256 halves
  const int tid = threadIdx.x;
  { const uint4* g = (const uint4*)(ws + WO_OFF);
    uint4* l = (uint4*)sWo;
#pragma unroll
    for (int i = 0; i < 16; ++i) l[tid + 256 * i] = g[tid + 256 * i]; }
  const _Float16* hb = ws + HBUF_OFF;
  const int row0 = blockIdx.x * 256;
  const int j = tid & 127, rh = tid >> 7;
  const float boj = bo[j];
  for (int it = 0; it < 32; ++it) {
    const int rbase = row0 + it * 8;
    __syncthreads();
    ((uint4*)sH)[tid] = ((const uint4*)(hb + (size_t)rbase * 256))[tid];
    __syncthreads();
#pragma unroll
    for (int rr = rh; rr < 8; rr += 2) {
      float y0 = 0.f, y1 = 0.f, y2 = 0.f, y3 = 0.f;
#pragma unroll 4
      for (int c = 0; c < 32; ++c) {
        h8 v = *(const h8*)&sH[rr * 256 + c * 8];
        h8 w = *(const h8*)&sWo[((size_t)c * 128 + j) * 8];
        dot8_4(v, w, y0, y1, y2, y3);
      }
      out[(size_t)(rbase + rr) * 128 + j] = y0 + y1 + y2 + y3 + boj;
    }
  }
}

extern "C" void kernel_launch(void* const* d_in, const int* in_sizes, int n_in,
                              void* d_out, int out_size, void* d_ws, size_t ws_size,
                              hipStream_t stream) {
  const float* x   = (const float*)d_in[0];
  const float* ts  = (const float*)d_in[1];
  const float* Wb  = (const float*)d_in[2];
  const float* bb  = (const float*)d_in[3];
  const float* W1  = (const float*)d_in[4];
  const float* bf1 = (const float*)d_in[5];
  const float* W2  = (const float*)d_in[6];
  const float* bf2 = (const float*)d_in[7];
  const float* W3  = (const float*)d_in[8];
  const float* bta = (const float*)d_in[9];
  const float* W4  = (const float*)d_in[10];
  const float* btb = (const float*)d_in[11];
  const float* Wo  = (const float*)d_in[12];
  const float* bo  = (const float*)d_in[13];
  float* out = (float*)d_out;
  _Float16* ws = (_Float16*)d_ws;

  pack_w<<<WS_HALVES / 256, 256, 0, stream>>>(Wb, W1, W2, W3, W4, Wo, ws);

  if (ws_size >= WS_PAIR_BYTES) {
    zmbox<<<MBOX_WORDS / 256, 256, 0, stream>>>(
        (unsigned long long*)((char*)d_ws + MBOX_BYTE_OFF));
    xgemm<<<(Bn * Sn) / 64, 256, 0, stream>>>(x, ws, ws + XC_OFF);
    hipFuncSetAttribute((const void*)cfc6,
                        hipFuncAttributeMaxDynamicSharedMemorySize, DYN6);
    cfc6<<<2 * Bn, NT1, DYN6, stream>>>(
        ts, bb, bf1, bf2, bta, btb, ws,
        (unsigned long long*)((char*)d_ws + MBOX_BYTE_OFF));
    hipFuncSetAttribute((const void*)ygemm,
                        hipFuncAttributeMaxDynamicSharedMemorySize, SMEMY);
    ygemm<<<(Bn * Sn) / 256, 256, SMEMY, stream>>>(ws, bo, out);
  } else if (ws_size >= WS_FULL_BYTES) {
    xgemm<<<(Bn * Sn) / 64, 256, 0, stream>>>(x, ws, ws + XC_OFF);
    hipFuncSetAttribute((const void*)(cfc5<1, 0>),
                        hipFuncAttributeMaxDynamicSharedMemorySize, DYN_SMEM);
    cfc5<1, 0><<<Bn, NT1, DYN_SMEM, stream>>>(x, ts, bb, bf1, bf2, bta, btb, bo, ws, out);
    hipFuncSetAttribute((const void*)ygemm,
                        hipFuncAttributeMaxDynamicSharedMemorySize, SMEMY);
    ygemm<<<(Bn * Sn) / 256, 256, SMEMY, stream>>>(ws, bo, out);
  } else if (ws_size >= WS_SPLIT_BYTES) {
    hipFuncSetAttribute((const void*)(cfc5<0, 0>),
                        hipFuncAttributeMaxDynamicSharedMemorySize, DYN_SMEM);
    cfc5<0, 0><<<Bn, NT1, DYN_SMEM, stream>>>(x, ts, bb, bf1, bf2, bta, btb, bo, ws, out);
    hipFuncSetAttribute((const void*)ygemm,
                        hipFuncAttributeMaxDynamicSharedMemorySize, SMEMY);
    ygemm<<<(Bn * Sn) / 256, 256, SMEMY, stream>>>(ws, bo, out);
  } else {
    hipFuncSetAttribute((const void*)(cfc5<0, 1>),
                        hipFuncAttributeMaxDynamicSharedMemorySize, DYN_SMEM);
    cfc5<0, 1><<<Bn, NT1, DYN_SMEM, stream>>>(x, ts, bb, bf1, bf2, bta, btb, bo, ws, out);
  }
}